// Round 11
// baseline (530.990 us; speedup 1.0000x reference)
//
#include <hip/hip_runtime.h>
#include <hip/hip_fp16.h>

#define BB 512
#define TT 2048

typedef _Float16 half2v __attribute__((ext_vector_type(2)));

// ---------- fast math helpers ----------
__device__ __forceinline__ float fexp2(float x){ return __builtin_amdgcn_exp2f(x); }
__device__ __forceinline__ float frcp(float x){ return __builtin_amdgcn_rcpf(x); }
__device__ __forceinline__ float sigm(float x){ return frcp(1.f + fexp2(-1.4426950408889634f*x)); }
__device__ __forceinline__ float tanhfast(float x){ return 1.f - 2.f*frcp(1.f + fexp2(2.8853900817779268f*x)); }

#define QB(v, ctrl) __int_as_float(__builtin_amdgcn_mov_dpp(__float_as_int(v), (ctrl), 0xF, 0xF, true))
#define RL(v, l)    __builtin_amdgcn_readlane((v), (l))

// ---------- pass 1: xg[b][tg][e][u] = f16( -k_q * preact ), 53 rows ----------
// rows 0..51: e = q*13+j, preact = x·W_ih^T + b_ih + b_hh, k_q = 2*log2e for q==2 else log2e
// row 52:     constant -log2e * fc_b  (FC fusion row)
// u = t&7; row stride 16B; tg stride 848B.
__global__ __launch_bounds__(256) void k_xg3(const float* __restrict__ x,
                                             const float* __restrict__ Wih,
                                             const float* __restrict__ bih,
                                             const float* __restrict__ bhh,
                                             const float* __restrict__ fcb,
                                             unsigned* __restrict__ xg_u)
{
  __shared__ float    xs[13*256];
  __shared__ unsigned ot[32*212];      // 32 tg x 424 ushorts (53 rows x 8) = 848B/tg
  const int tid = threadIdx.x;
  const int b   = blockIdx.x >> 3;
  const int t0  = (blockIdx.x & 7) << 8;

  const float* xsrc = x + ((size_t)b*TT + t0)*13;
  #pragma unroll
  for (int it=0; it<13; ++it) xs[tid + it*256] = xsrc[tid + it*256];
  __syncthreads();

  float xv[13];
  #pragma unroll
  for (int k=0;k<13;k++) xv[k] = xs[tid*13+k];

  const int tgl = tid >> 3, u = tid & 7;
  unsigned short* otp = (unsigned short*)ot;
  #pragma unroll 2
  for (int g=0; g<52; ++g){            // g = q*13+j; q==2 <=> 26<=g<39
    float acc = bih[g] + bhh[g];
    #pragma unroll
    for (int k=0;k<13;k++) acc = fmaf(Wih[g*13+k], xv[k], acc);
    const float sc = (g>=26 && g<39) ? -2.8853900817779268f : -1.4426950408889634f;
    otp[tgl*424 + g*8 + u] = __half_as_ushort(__float2half(acc*sc));
  }
  // FC row (52): constant -log2e*fc_b
  otp[tgl*424 + 52*8 + u] =
      __half_as_ushort(__float2half(-1.4426950408889634f * fcb[0]));
  __syncthreads();

  // straight copy: LDS layout == xg layout (53 rows x 8 f16 = 212 uints/tg)
  unsigned* dst = xg_u + (size_t)b*(256*212) + (size_t)(blockIdx.x & 7)*(32*212);
  #pragma unroll
  for (int it=0; it<27; ++it){
    int i2 = tid + it*256;
    if (i2 < 32*212) dst[i2] = ot[i2];
  }
}

// ---------- pass 2: TWO chains per wave, time-interleaved ----------
// Wave handles batches 2*blk and 2*blk+1. lane 4j+q owns gate q of unit j for BOTH
// chains (shared w[], independent state). Independent chains fill each other's
// trans/readlane latency stalls. lane 52 computes the FC output on both chains.
__global__ __launch_bounds__(64, 1) void k_rec11(const float* __restrict__ Whh,
                                                 const float* __restrict__ fcw,
                                                 const float* __restrict__ fcb,
                                                 const unsigned short* __restrict__ xg,
                                                 float* __restrict__ out)
{
  const int lane = threadIdx.x;
  const int bA   = blockIdx.x*2;
  const int bB   = bA + 1;
  const int q    = lane & 3;
  const int j    = lane >> 2;
  const int jc   = (j < 13) ? j : 12;
  const int e    = (lane == 52) ? 52 : q*13 + jc;

  const float kq = (q==2) ? -2.8853900817779268f : -1.4426950408889634f;
  const float gm = (q==2) ? -5.7707801635558536f : 1.f;
  const float ga = (q==2) ?  2.8853900817779268f : 0.f;
  const float fcbias = -1.4426950408889634f * fcb[0];

  const float* wsrc = (lane == 52) ? fcw : (Whh + e*13);
  float w[13];
  #pragma unroll
  for (int k=0;k<13;k++) w[k] = wsrc[k]*kq;

  const char* gbaseA = (const char*)xg + (size_t)bA*(256*848) + (size_t)e*16;
  const char* gbaseB = (const char*)xg + (size_t)bB*(256*848) + (size_t)e*16;

  // per-chain state
  float hA=0.f, c_A=0.f, hB=0.f, c_B=0.f;
  float hb0A=0,hb1A=0,hb2A=0,hb3A=0,hb4A=0,hb5A=0,hb6A=0,hb7A=0,hb8A=0,hb9A=0,hb10A=0,hb11A=0,hb12A=0;
  float hb0B=0,hb1B=0,hb2B=0,hb3B=0,hb4B=0,hb5B=0,hb6B=0,hb7B=0,hb8B=0,hb9B=0,hb10B=0,hb11B=0,hb12B=0;
  float p0A=0,p1A=0,p2A=0,p3A=0,p4A=0,p5A=0,p6A=0,p7A=0;
  float p0B=0,p1B=0,p2B=0,p3B=0,p4B=0,p5B=0,p6B=0,p7B=0;
  float* opA = out + (size_t)bA*TT;
  float* opB = out + (size_t)bB*TT;
  bool firstA = true, firstB = true;

#define CAPT(S, gv_, u_) do {                                                 \
    if ((u_)==1) p0##S=(gv_); else if ((u_)==2) p1##S=(gv_);                  \
    else if ((u_)==3) p2##S=(gv_); else if ((u_)==4) p3##S=(gv_);             \
    else if ((u_)==5) p4##S=(gv_); else if ((u_)==6) p5##S=(gv_);             \
    else if ((u_)==7) p6##S=(gv_);                                            \
    else { p7##S=(gv_);                                                       \
      if (!first##S){                                                         \
        if (lane == 52){                                                      \
          float4* o4 = (float4*)op##S;                                        \
          o4[0] = make_float4(p0##S,p1##S,p2##S,p3##S);                       \
          o4[1] = make_float4(p4##S,p5##S,p6##S,p7##S);                       \
        }                                                                     \
        op##S += 8;                                                           \
      }                                                                       \
      first##S = false;                                                       \
    }                                                                         \
  } while(0)

#define STEPC(S, xv_, u_) do {                                                \
    float dA_ = fmaf(w[0], hb0##S, (xv_));                                    \
    dA_ = fmaf(w[1], hb1##S, dA_);                                            \
    dA_ = fmaf(w[2], hb2##S, dA_);                                            \
    dA_ = fmaf(w[3], hb3##S, dA_);                                            \
    dA_ = fmaf(w[4], hb4##S, dA_);                                            \
    float dB_ = w[5]*hb5##S;                                                  \
    dB_ = fmaf(w[6], hb6##S, dB_);                                            \
    dB_ = fmaf(w[7], hb7##S, dB_);                                            \
    dB_ = fmaf(w[8], hb8##S, dB_);                                            \
    float dC_ = w[9]*hb9##S;                                                  \
    dC_ = fmaf(w[10], hb10##S, dC_);                                          \
    dC_ = fmaf(w[11], hb11##S, dC_);                                          \
    dC_ = fmaf(w[12], hb12##S, dC_);                                          \
    float s_  = (dB_ + dC_) + dA_;                                            \
    float r_  = frcp(1.f + fexp2(s_));                                        \
    float g_  = fmaf(gm, r_, ga);                                             \
    CAPT(S, g_, u_);                                                          \
    float ggb_ = QB(g_, 0xAA);                                                \
    float gfb_ = QB(g_, 0x55);                                                \
    float gob_ = QB(g_, 0xFF);                                                \
    float go2_ = gob_ + gob_;                                                 \
    c_##S = fmaf(gfb_, c_##S, g_*ggb_);                                       \
    float r2_ = frcp(1.f + fexp2(c_##S));                                     \
    h##S = fmaf(go2_, r2_, -gob_);                                            \
    int hv_ = __float_as_int(h##S);                                           \
    hb0##S  = __int_as_float(RL(hv_, 0));                                     \
    hb1##S  = __int_as_float(RL(hv_, 4));                                     \
    hb2##S  = __int_as_float(RL(hv_, 8));                                     \
    hb3##S  = __int_as_float(RL(hv_, 12));                                    \
    hb4##S  = __int_as_float(RL(hv_, 16));                                    \
    hb5##S  = __int_as_float(RL(hv_, 20));                                    \
    hb6##S  = __int_as_float(RL(hv_, 24));                                    \
    hb7##S  = __int_as_float(RL(hv_, 28));                                    \
    hb8##S  = __int_as_float(RL(hv_, 32));                                    \
    hb9##S  = __int_as_float(RL(hv_, 36));                                    \
    hb10##S = __int_as_float(RL(hv_, 40));                                    \
    hb11##S = __int_as_float(RL(hv_, 44));                                    \
    hb12##S = __int_as_float(RL(hv_, 48));                                    \
  } while(0)

#define XLO(w_) (float)(__builtin_bit_cast(half2v, (w_)).x)
#define XHI(w_) (float)(__builtin_bit_cast(half2v, (w_)).y)

  // depth-2 prefetch queues per chain (prefetch distance = 16 steps)
  uint4 qA0 = *(const uint4*)(gbaseA);
  uint4 qA1 = *(const uint4*)(gbaseA + 848);
  uint4 qB0 = *(const uint4*)(gbaseB);
  uint4 qB1 = *(const uint4*)(gbaseB + 848);

  for (int tg=0; tg<256; ++tg){
    const int pf = (tg+2 < 256) ? tg+2 : 255;
    uint4 cA = qA0; qA0 = qA1; qA1 = *(const uint4*)(gbaseA + (size_t)pf*848);
    uint4 cB = qB0; qB0 = qB1; qB1 = *(const uint4*)(gbaseB + (size_t)pf*848);

    STEPC(A, XLO(cA.x), 0); STEPC(B, XLO(cB.x), 0);
    STEPC(A, XHI(cA.x), 1); STEPC(B, XHI(cB.x), 1);
    STEPC(A, XLO(cA.y), 2); STEPC(B, XLO(cB.y), 2);
    STEPC(A, XHI(cA.y), 3); STEPC(B, XHI(cB.y), 3);
    STEPC(A, XLO(cA.z), 4); STEPC(B, XLO(cB.z), 4);
    STEPC(A, XHI(cA.z), 5); STEPC(B, XHI(cB.z), 5);
    STEPC(A, XLO(cA.w), 6); STEPC(B, XLO(cB.w), 6);
    STEPC(A, XHI(cA.w), 7); STEPC(B, XHI(cB.w), 7);
  }

  // epilogue: out[2047] for both chains
  {
    float s = fcbias;
    s = fmaf(w[0],  hb0A,  s);  s = fmaf(w[1],  hb1A,  s);
    s = fmaf(w[2],  hb2A,  s);  s = fmaf(w[3],  hb3A,  s);
    s = fmaf(w[4],  hb4A,  s);  s = fmaf(w[5],  hb5A,  s);
    s = fmaf(w[6],  hb6A,  s);  s = fmaf(w[7],  hb7A,  s);
    s = fmaf(w[8],  hb8A,  s);  s = fmaf(w[9],  hb9A,  s);
    s = fmaf(w[10], hb10A, s);  s = fmaf(w[11], hb11A, s);
    s = fmaf(w[12], hb12A, s);
    float rA = frcp(1.f + fexp2(s));
    float t = fcbias;
    t = fmaf(w[0],  hb0B,  t);  t = fmaf(w[1],  hb1B,  t);
    t = fmaf(w[2],  hb2B,  t);  t = fmaf(w[3],  hb3B,  t);
    t = fmaf(w[4],  hb4B,  t);  t = fmaf(w[5],  hb5B,  t);
    t = fmaf(w[6],  hb6B,  t);  t = fmaf(w[7],  hb7B,  t);
    t = fmaf(w[8],  hb8B,  t);  t = fmaf(w[9],  hb9B,  t);
    t = fmaf(w[10], hb10B, t);  t = fmaf(w[11], hb11B, t);
    t = fmaf(w[12], hb12B, t);
    float rB = frcp(1.f + fexp2(t));
    if (lane == 52){
      float4* o4 = (float4*)opA;          // opA == out + bA*TT + 2040
      o4[0] = make_float4(p0A,p1A,p2A,p3A);
      o4[1] = make_float4(p4A,p5A,p6A,rA);
      float4* o5 = (float4*)opB;
      o5[0] = make_float4(p0B,p1B,p2B,p3B);
      o5[1] = make_float4(p4B,p5B,p6B,rB);
    }
  }

#undef STEPC
#undef CAPT
#undef XLO
#undef XHI
}

// ---------- fallback (no workspace) ----------
__global__ __launch_bounds__(64) void k_rec_fb(
    const float* __restrict__ x,   const float* __restrict__ Whh,
    const float* __restrict__ Wih, const float* __restrict__ bih, const float* __restrict__ bhh,
    const float* __restrict__ fcw, const float* __restrict__ fcb,
    float* __restrict__ out)
{
  const int lane = threadIdx.x;
  const int c    = lane >> 4;
  const int j    = lane & 15;
  const int b    = blockIdx.x*4 + c;
  const bool act = (j < 13);
  const int jj   = act ? j : 0;

  float whh[4][13], wih[4][13], bias[4];
  #pragma unroll
  for (int q=0;q<4;q++){
    #pragma unroll
    for (int k=0;k<13;k++){
      float w1 = Whh[(q*13+jj)*13 + k];
      float w2 = Wih[(q*13+jj)*13 + k];
      whh[q][k] = act ? w1 : 0.f;
      wih[q][k] = act ? w2 : 0.f;
    }
    bias[q] = bih[q*13+jj] + bhh[q*13+jj];
  }
  const float fcwj = act ? fcw[jj] : 0.f;
  const float fcb0 = fcb[0];

  const float* xpf = x + (size_t)b*(TT*13) + jj;
  float* op = out + (size_t)b*TT;

  float h = 0.f, cs = 0.f;
  float xsc = *xpf;

  for (int t=0; t<TT; ++t){
    float xscn = 0.f;
    if (t+1 < TT) { xpf += 13; xscn = *xpf; }

    float hb[13], xb[13];
    {
      int hbits = __float_as_int(h);
      int xbits = __float_as_int(xsc);
      #define HB(k) hb[k] = __int_as_float(__builtin_amdgcn_ds_swizzle(hbits, ((k)<<5)|0x10)); \
                    xb[k] = __int_as_float(__builtin_amdgcn_ds_swizzle(xbits, ((k)<<5)|0x10));
      HB(0) HB(1) HB(2) HB(3) HB(4) HB(5) HB(6) HB(7) HB(8) HB(9) HB(10) HB(11) HB(12)
      #undef HB
    }
    float a0 = bias[0], a1 = bias[1], a2 = bias[2], a3 = bias[3];
    #pragma unroll
    for (int k=0;k<13;k++){
      float xk = xb[k], hk = hb[k];
      a0 += wih[0][k]*xk + whh[0][k]*hk;
      a1 += wih[1][k]*xk + whh[1][k]*hk;
      a2 += wih[2][k]*xk + whh[2][k]*hk;
      a3 += wih[3][k]*xk + whh[3][k]*hk;
    }
    float ig = sigm(a0), fg = sigm(a1), gg = tanhfast(a2), og = sigm(a3);
    cs = fg*cs + ig*gg;
    h  = og * tanhfast(cs);

    float p = act ? fcwj*h : 0.f;
    #define RED(m) p += __int_as_float(__builtin_amdgcn_ds_swizzle(__float_as_int(p), ((m)<<10)|0x1F));
    RED(1) RED(2) RED(4) RED(8)
    #undef RED
    if (j == 0) op[t] = sigm(p + fcb0);
    xsc = xscn;
  }
}

extern "C" void kernel_launch(void* const* d_in, const int* in_sizes, int n_in,
                              void* d_out, int out_size, void* d_ws, size_t ws_size,
                              hipStream_t stream)
{
  const float* x   = (const float*)d_in[0];
  const float* Wih = (const float*)d_in[1];
  const float* Whh = (const float*)d_in[2];
  const float* bih = (const float*)d_in[3];
  const float* bhh = (const float*)d_in[4];
  const float* fcw = (const float*)d_in[5];
  const float* fcb = (const float*)d_in[6];
  float* out = (float*)d_out;

  const size_t XG_BYTES = (size_t)BB*256*848;     // 111,149,056  f16 [b][tg][53][8]

  if (ws_size >= XG_BYTES){
    unsigned* xg = (unsigned*)d_ws;
    k_xg3<<<dim3(BB*8), dim3(256), 0, stream>>>(x, Wih, bih, bhh, fcb, xg);
    k_rec11<<<dim3(BB/2), dim3(64), 0, stream>>>(Whh, fcw, fcb,
                                                 (const unsigned short*)xg, out);
  } else {
    k_rec_fb<<<dim3(BB/4), dim3(64), 0, stream>>>(x, Whh, Wih, bih, bhh, fcw, fcb, out);
  }
}